// Round 8
// baseline (418.862 us; speedup 1.0000x reference)
//
#include <hip/hip_runtime.h>
#include <hip/hip_cooperative_groups.h>
#include <math.h>

namespace cg = cooperative_groups;

#define B 4
#define N 256
#define DIN 4
#define D 64
#define NH 4
#define NL 2
#define DH 16

constexpr float EPS = 1e-5f;
constexpr float SLOPE = 0.01f;

// ---------------------------------------------------------------------------
// Transformer layer tail (R2's proven k_layer body): flash-split attention
// (wave = (head, key-half), 128 keys/wave in regs, LDS merge) + split-K-2
// post phases. Weights read direct from global (L2-resident). x carried in
// the xv register (token = w&3 for every thread).
// ---------------------------------------------------------------------------
template <bool FUSE, bool WRITE_X>
__device__ __forceinline__ void layer_body(
    int lane, int w, int b, int q0, float& xv,
    const float* __restrict__ kg, const float* __restrict__ vg,
    const float* __restrict__ Wo_, const float* __restrict__ bo_,
    const float* __restrict__ l1g_, const float* __restrict__ l1b_,
    const float* __restrict__ Wff1_, const float* __restrict__ bff1_,
    const float* __restrict__ Wff2_, const float* __restrict__ bff2_,
    const float* __restrict__ l2g_, const float* __restrict__ l2b_,
    const float* __restrict__ Wqn_, const float* __restrict__ bqn_,
    const float* __restrict__ Wkn_, const float* __restrict__ bkn_,
    const float* __restrict__ Wvn_, const float* __restrict__ bvn_,
    float* __restrict__ kOut, float* __restrict__ vOut,
    float* qsh, float* attS, float* xs, float* f1s,
    float* ppA, float* ppB, float* attO, float* attM, float* attL,
    float* __restrict__ xout)
{
    int ch = lane;
    int h_ = w & 3, half = w >> 2;
    int tok4 = h_, kh = half;
    int bh = b * NH + h_;
    const float* kb = kg + ((size_t)bh * N + half * 128) * DH;
    const float* vb = vg + ((size_t)bh * N + half * 128) * DH;
    float4 Kr[2][4], Vr[2][4];
#pragma unroll
    for (int j = 0; j < 2; ++j) {
        int key = lane + 64 * j;
#pragma unroll
        for (int c = 0; c < 4; ++c) {
            Kr[j][c] = *(const float4*)(kb + (size_t)key * DH + 4 * c);
            Vr[j][c] = *(const float4*)(vb + (size_t)key * DH + 4 * c);
        }
    }
    float bo_r = bo_[ch], l1g = l1g_[ch], l1b = l1b_[ch];
    float bf1_r = bff1_[kh * D + ch];
    float bf2_r = bff2_[ch], l2g = l2g_[ch], l2b = l2b_[ch];
    float bq_r = 0.f, bk_r = 0.f, bv_r = 0.f;
    if (FUSE) { bq_r = bqn_[ch]; bk_r = bkn_[ch]; bv_r = bvn_[ch]; }
    // prefetch this wave's Wo slice; consumed after the attention barrier
    float wo[32];
#pragma unroll
    for (int i = 0; i < 32; ++i) wo[i] = Wo_[(kh * 32 + i) * D + ch];

    // ---- partial flash attention over this wave's 128-key half ----
#pragma unroll
    for (int qq = 0; qq < 4; ++qq) {
        const float4* qp4 = (const float4*)(qsh + qq * D + h_ * DH);
        float4 qv[4] = {qp4[0], qp4[1], qp4[2], qp4[3]};
        float s0 = 0.f, s1 = 0.f;
#pragma unroll
        for (int c = 0; c < 4; ++c) {
            s0 += qv[c].x*Kr[0][c].x + qv[c].y*Kr[0][c].y + qv[c].z*Kr[0][c].z + qv[c].w*Kr[0][c].w;
            s1 += qv[c].x*Kr[1][c].x + qv[c].y*Kr[1][c].y + qv[c].z*Kr[1][c].z + qv[c].w*Kr[1][c].w;
        }
        float m = fmaxf(s0, s1);
#pragma unroll
        for (int off = 32; off > 0; off >>= 1) m = fmaxf(m, __shfl_xor(m, off));
        float p0 = __expf((s0 - m) * 0.25f);   // 1/sqrt(DH) folded in
        float p1 = __expf((s1 - m) * 0.25f);
        float lsum = p0 + p1;
#pragma unroll
        for (int off = 32; off > 0; off >>= 1) lsum += __shfl_xor(lsum, off);
        float o[DH];
#pragma unroll
        for (int c = 0; c < 4; ++c) {
            o[4*c+0] = p0 * Vr[0][c].x + p1 * Vr[1][c].x;
            o[4*c+1] = p0 * Vr[0][c].y + p1 * Vr[1][c].y;
            o[4*c+2] = p0 * Vr[0][c].z + p1 * Vr[1][c].z;
            o[4*c+3] = p0 * Vr[0][c].w + p1 * Vr[1][c].w;
        }
#pragma unroll
        for (int d = 0; d < DH; ++d)
#pragma unroll
            for (int off = 32; off > 0; off >>= 1) o[d] += __shfl_xor(o[d], off);
        if (lane == 0) {
#pragma unroll
            for (int d = 0; d < DH; ++d) attO[half * 4 * D + qq * D + h_ * DH + d] = o[d];
            attM[half * 16 + qq * 4 + h_] = m;
            attL[half * 16 + qq * 4 + h_] = lsum;
        }
    }
    __syncthreads();

    // ---- merge the two key-halves (wave = query qq) ----
    if (w < 4) {
        int qq = w;
        int head = ch >> 4;
        float m0 = attM[qq * 4 + head], m1 = attM[16 + qq * 4 + head];
        float l0 = attL[qq * 4 + head], l1 = attL[16 + qq * 4 + head];
        float M = fmaxf(m0, m1);
        float e0 = __expf((m0 - M) * 0.25f);
        float e1 = __expf((m1 - M) * 0.25f);
        float rl = 1.f / (l0 * e0 + l1 * e1);
        attS[qq * D + ch] = (attO[qq * D + ch] * e0 + attO[4 * D + qq * D + ch] * e1) * rl;
    }
    __syncthreads();

    // ---- O-proj (split-K-2) ----
    {
        const float4* ar4 = (const float4*)(attS + tok4 * D + kh * 32);
        float a0=0.f, a1=0.f, a2=0.f, a3=0.f;
#pragma unroll
        for (int k4 = 0; k4 < 8; ++k4) {
            float4 av = ar4[k4];
            a0 += av.x * wo[k4*4+0];
            a1 += av.y * wo[k4*4+1];
            a2 += av.z * wo[k4*4+2];
            a3 += av.w * wo[k4*4+3];
        }
        ppA[w * 192 + ch] = (a0+a1)+(a2+a3);
    }
    __syncthreads();
    float oo = bo_r + ppA[tok4 * 192 + ch] + ppA[(tok4 + 4) * 192 + ch];
    float r = xv + oo;
    float s1v = r, sq1 = r * r;
#pragma unroll
    for (int off = 32; off > 0; off >>= 1) {
        s1v += __shfl_xor(s1v, off);
        sq1 += __shfl_xor(sq1, off);
    }
    float mean1 = s1v * (1.0f / D), var1 = sq1 * (1.0f / D) - mean1 * mean1;
    float x1 = l1g * (r - mean1) * rsqrtf(var1 + EPS) + l1b;
    if (kh == 0) xs[tok4 * D + ch] = x1;
    __syncthreads();

    // ---- FFN1 (split-K-2, both output halves) ----
    {
        const float4* xr4 = (const float4*)(xs + tok4 * D + kh * 32);
        float u0=0.f,u1=0.f,u2=0.f,u3=0.f, g0=0.f,g1=0.f,g2=0.f,g3=0.f;
#pragma unroll
        for (int k4 = 0; k4 < 8; ++k4) {
            float4 xx = xr4[k4];
            int kk = kh * 32 + k4 * 4;
            u0 += xx.x * Wff1_[(kk+0)*128 + ch];
            u1 += xx.y * Wff1_[(kk+1)*128 + ch];
            u2 += xx.z * Wff1_[(kk+2)*128 + ch];
            u3 += xx.w * Wff1_[(kk+3)*128 + ch];
            g0 += xx.x * Wff1_[(kk+0)*128 + 64 + ch];
            g1 += xx.y * Wff1_[(kk+1)*128 + 64 + ch];
            g2 += xx.z * Wff1_[(kk+2)*128 + 64 + ch];
            g3 += xx.w * Wff1_[(kk+3)*128 + 64 + ch];
        }
        ppB[w * 192 + ch] = (u0+u1)+(u2+u3);
        ppB[w * 192 + 64 + ch] = (g0+g1)+(g2+g3);
    }
    __syncthreads();
    f1s[tok4 * 128 + kh * 64 + ch] =
        fmaxf(ppB[tok4*192 + kh*64 + ch] + ppB[(tok4+4)*192 + kh*64 + ch] + bf1_r, 0.f);
    __syncthreads();

    // ---- FFN2 (split-K-2 over 128) ----
    {
        const float4* fr4 = (const float4*)(f1s + tok4 * 128 + kh * 64);
        float e0=0.f,e1=0.f,e2=0.f,e3=0.f;
#pragma unroll
        for (int k4 = 0; k4 < 16; ++k4) {
            float4 fv = fr4[k4];
            int kk = kh * 64 + k4 * 4;
            e0 += fv.x * Wff2_[(kk+0)*D + ch];
            e1 += fv.y * Wff2_[(kk+1)*D + ch];
            e2 += fv.z * Wff2_[(kk+2)*D + ch];
            e3 += fv.w * Wff2_[(kk+3)*D + ch];
        }
        ppA[w * 192 + ch] = (e0+e1)+(e2+e3);
    }
    __syncthreads();
    float o2 = bf2_r + ppA[tok4*192 + ch] + ppA[(tok4+4)*192 + ch];
    float r2 = x1 + o2;
    float s2 = r2, sq2 = r2 * r2;
#pragma unroll
    for (int off = 32; off > 0; off >>= 1) {
        s2 += __shfl_xor(s2, off);
        sq2 += __shfl_xor(sq2, off);
    }
    float mean2 = s2 * (1.0f / D), var2 = sq2 * (1.0f / D) - mean2 * mean2;
    float xnew = l2g * (r2 - mean2) * rsqrtf(var2 + EPS) + l2b;
    xv = xnew;
    if (WRITE_X && kh == 0) xout[((size_t)b * N + q0 + tok4) * D + ch] = xnew;

    // ---- fused next-layer QKV (q -> LDS, k/v -> double buffer) ----
    if (FUSE) {
        if (kh == 0) attS[tok4 * D + ch] = xnew;   // attS reads done pre-O-proj
        __syncthreads();
        const float4* xr4 = (const float4*)(attS + tok4 * D + kh * 32);
        float aq0=0.f,aq1=0.f, ak0=0.f,ak1=0.f, av0=0.f,av1=0.f;
#pragma unroll
        for (int k4 = 0; k4 < 8; ++k4) {
            float4 xx = xr4[k4];
            int kk = kh * 32 + k4 * 4;
            aq0 += xx.x * Wqn_[(kk+0)*D+ch] + xx.z * Wqn_[(kk+2)*D+ch];
            aq1 += xx.y * Wqn_[(kk+1)*D+ch] + xx.w * Wqn_[(kk+3)*D+ch];
            ak0 += xx.x * Wkn_[(kk+0)*D+ch] + xx.z * Wkn_[(kk+2)*D+ch];
            ak1 += xx.y * Wkn_[(kk+1)*D+ch] + xx.w * Wkn_[(kk+3)*D+ch];
            av0 += xx.x * Wvn_[(kk+0)*D+ch] + xx.z * Wvn_[(kk+2)*D+ch];
            av1 += xx.y * Wvn_[(kk+1)*D+ch] + xx.w * Wvn_[(kk+3)*D+ch];
        }
        ppB[w*192 + ch] = aq0 + aq1;
        ppB[w*192 + 64 + ch] = ak0 + ak1;
        ppB[w*192 + 128 + ch] = av0 + av1;
        __syncthreads();
        if (kh == 0) {
            int head = ch >> 4, dh = ch & (DH - 1);
            size_t oidx = (((size_t)(b * NH + head)) * N + (q0 + tok4)) * DH + dh;
            qsh[tok4 * D + ch] = bq_r + ppB[tok4*192 + ch] + ppB[(tok4+4)*192 + ch];
            kOut[oidx] = bk_r + ppB[tok4*192 + 64 + ch] + ppB[(tok4+4)*192 + 64 + ch];
            vOut[oidx] = bv_r + ppB[tok4*192 + 128 + ch] + ppB[(tok4+4)*192 + 128 + ch];
        }
    }
}

// ---------------------------------------------------------------------------
// Single cooperative kernel, R3's proven-launchable shape: 256 blocks x 512
// threads (1 block/CU guaranteed co-resident), __launch_bounds__(512,2)
// (256-VGPR cap), ~21 KB LDS (no weight staging). Block cb owns tokens
// q0..q0+3 of batch b in every token phase; h/q/x never touch global. Only
// rs, bnacc, K/V (double-buffered) cross blocks, guarded by grid.sync().
// ---------------------------------------------------------------------------
__global__ void __launch_bounds__(512, 2) k_all(
    const float* __restrict__ feature, const float* __restrict__ W1,
    const float* __restrict__ b1, const float* __restrict__ mw,
    const float* __restrict__ mb, const float* __restrict__ bn_g,
    const float* __restrict__ bn_b,
    const float* __restrict__ Wq, const float* __restrict__ bq,
    const float* __restrict__ Wk, const float* __restrict__ bk,
    const float* __restrict__ Wv, const float* __restrict__ bv,
    const float* __restrict__ Wo, const float* __restrict__ bo,
    const float* __restrict__ ln1g, const float* __restrict__ ln1b,
    const float* __restrict__ Wff1, const float* __restrict__ bff1,
    const float* __restrict__ Wff2, const float* __restrict__ bff2,
    const float* __restrict__ ln2g, const float* __restrict__ ln2b,
    float* __restrict__ rs, float* __restrict__ bnacc,
    float* __restrict__ k0, float* __restrict__ v0,
    float* __restrict__ k1, float* __restrict__ v1,
    float* __restrict__ xout)
{
    __shared__ float part1[32];
    __shared__ float part2[8][10];
    __shared__ float gacc[20];
    __shared__ float hs[4][D];
    __shared__ __align__(16) float qsh[4 * D];
    __shared__ __align__(16) float attS[4 * D];
    __shared__ __align__(16) float xs[4 * D];
    __shared__ __align__(16) float f1s[4 * 2 * D];
    __shared__ __align__(16) float ppA[8 * 192];
    __shared__ __align__(16) float ppB[8 * 192];
    __shared__ __align__(16) float attO[2 * 4 * D];
    __shared__ float attM[32], attL[32];

    cg::grid_group grid = cg::this_grid();
    int t = threadIdx.x, lane = t & 63, w = t >> 6, ch = lane;
    int cb = blockIdx.x;
    int b = cb >> 6, q0 = (cb & 63) * 4;

    if (cb == 0 && t < 128) bnacc[t] = 0.f;

    // ---- M/C projection in registers (redundant per wave; proven R5/R6) ----
    float w1v[4];
#pragma unroll
    for (int kk = 0; kk < 4; ++kk) w1v[kk] = W1[kk * D + lane];
    float b1v = b1[lane];
    float Mreg[16], Creg[4];
#pragma unroll
    for (int n = 0; n < 4; ++n) {
        float mwv = mw[n * D + lane];
        float p0 = w1v[0] * mwv, p1 = w1v[1] * mwv;
        float p2 = w1v[2] * mwv, p3 = w1v[3] * mwv;
        float pc = b1v * mwv;
#pragma unroll
        for (int off = 32; off > 0; off >>= 1) {
            p0 += __shfl_xor(p0, off); p1 += __shfl_xor(p1, off);
            p2 += __shfl_xor(p2, off); p3 += __shfl_xor(p3, off);
            pc += __shfl_xor(pc, off);
        }
        Mreg[n * 4 + 0] = p0; Mreg[n * 4 + 1] = p1;
        Mreg[n * 4 + 2] = p2; Mreg[n * 4 + 3] = p3;
        Creg[n] = pc + mb[n];
    }

    // ---- P1: rowsum (R6 k_rowsum body). wave = (row r=w&3, half mh) ----
    {
        int r = w & 3, mh = w >> 2;
        int bi = cb * 4 + r;
        const float4* fb = (const float4*)feature + (size_t)bi * N;
        float4 f0 = fb[lane + 64 * (mh * 2 + 0)];
        float4 f1 = fb[lane + 64 * (mh * 2 + 1)];
        float sn[4] = {0.f, 0.f, 0.f, 0.f};
#pragma unroll
        for (int mm = 0; mm < 2; ++mm) {
            float4 f = (mm == 0) ? f0 : f1;
#pragma unroll
            for (int n = 0; n < 4; ++n) {
                float s = Creg[n] + f.x * Mreg[n*4+0] + f.y * Mreg[n*4+1]
                                  + f.z * Mreg[n*4+2] + f.w * Mreg[n*4+3];
                s = (s >= 0.f) ? s : SLOPE * s;
                sn[n] += __expf(s);
            }
        }
#pragma unroll
        for (int n = 0; n < 4; ++n)
#pragma unroll
            for (int off = 32; off > 0; off >>= 1) sn[n] += __shfl_xor(sn[n], off);
        if (lane == 0) {
#pragma unroll
            for (int n = 0; n < 4; ++n) part1[w * 4 + n] = sn[n];
        }
        __syncthreads();
        if (t < 16) {
            int rr = t >> 2, n = t & 3;
            rs[((size_t)(cb * 4 + rr)) * 4 + n] = part1[rr * 4 + n] + part1[(rr + 4) * 4 + n];
        }
    }
    __threadfence();
    grid.sync();   // rs complete

    // ---- P2: aggregate + h-proj (to LDS) + BN atomics (R6 body) ----
    {
        int i = t & 255, jh = t >> 8;
        const float4* fb2 = (const float4*)feature + ((size_t)(b * N + i) * N + q0 + jh * 2);
        float4 f[2];
        f[0] = fb2[0];
        f[1] = fb2[1];
        float4 r4 = *(const float4*)(rs + (size_t)(b * N + i) * 4);
        float rinv[4] = {1.f / r4.x, 1.f / r4.y, 1.f / r4.z, 1.f / r4.w};
        float acc[2][5];
#pragma unroll
        for (int jj = 0; jj < 2; ++jj) {
            float wbar = 0.f;
#pragma unroll
            for (int n = 0; n < 4; ++n) {
                float s = Creg[n] + f[jj].x * Mreg[n*4+0] + f[jj].y * Mreg[n*4+1]
                                  + f[jj].z * Mreg[n*4+2] + f[jj].w * Mreg[n*4+3];
                s = (s >= 0.f) ? s : SLOPE * s;
                wbar += __expf(s) * rinv[n];
            }
            wbar *= 0.25f;
            acc[jj][0] = wbar * f[jj].x; acc[jj][1] = wbar * f[jj].y;
            acc[jj][2] = wbar * f[jj].z; acc[jj][3] = wbar * f[jj].w;
            acc[jj][4] = wbar;
        }
#pragma unroll
        for (int jj = 0; jj < 2; ++jj)
#pragma unroll
            for (int c = 0; c < 5; ++c)
#pragma unroll
                for (int off = 32; off > 0; off >>= 1) acc[jj][c] += __shfl_xor(acc[jj][c], off);
        if (lane == 0) {
#pragma unroll
            for (int jj = 0; jj < 2; ++jj)
#pragma unroll
                for (int c = 0; c < 5; ++c) part2[w][jj * 5 + c] = acc[jj][c];
        }
        __syncthreads();
        if (t < 20) {
            int jj = t / 5, c = t - jj * 5;
            int g = jj >> 1, jjl = jj & 1;
            gacc[t] = part2[g*4+0][jjl*5+c] + part2[g*4+1][jjl*5+c]
                    + part2[g*4+2][jjl*5+c] + part2[g*4+3][jjl*5+c];
        }
        __syncthreads();
        if (t < 256) {   // wave w = token q0+w, lane = channel
            float hv = gacc[w * 5 + 4] * b1v;
#pragma unroll
            for (int kk = 0; kk < 4; ++kk) hv += gacc[w * 5 + kk] * w1v[kk];
            hs[w][lane] = hv;
        }
        __syncthreads();
        if (t < 64) {
            float s = hs[0][lane] + hs[1][lane] + hs[2][lane] + hs[3][lane];
            float sq = hs[0][lane]*hs[0][lane] + hs[1][lane]*hs[1][lane]
                     + hs[2][lane]*hs[2][lane] + hs[3][lane]*hs[3][lane];
            atomicAdd(bnacc + lane, s);
            atomicAdd(bnacc + D + lane, sq);
        }
    }
    __threadfence();
    grid.sync();   // bnacc complete

    // ---- P3: BN finalize + QKV layer 0 (R2 k_qkv0 body; q->LDS) ----
    float xv;
    {
        int tok4 = w & 3, kh = w >> 2;
        float mean = bnacc[ch] * (1.0f / (B * N));
        float var = bnacc[D + ch] * (1.0f / (B * N)) - mean * mean;
        float inv = rsqrtf(var + EPS);
        xv = bn_g[ch] * (hs[tok4][ch] - mean) * inv + bn_b[ch];
        if (kh == 0) xs[tok4 * D + ch] = xv;
        __syncthreads();
        const float4* xr4 = (const float4*)(xs + tok4 * D + kh * 32);
        float aq0=0.f,aq1=0.f, ak0=0.f,ak1=0.f, av0=0.f,av1=0.f;
#pragma unroll
        for (int k4 = 0; k4 < 8; ++k4) {
            float4 xx = xr4[k4];
            int kk = kh * 32 + k4 * 4;
            aq0 += xx.x * Wq[(kk+0)*D+ch] + xx.z * Wq[(kk+2)*D+ch];
            aq1 += xx.y * Wq[(kk+1)*D+ch] + xx.w * Wq[(kk+3)*D+ch];
            ak0 += xx.x * Wk[(kk+0)*D+ch] + xx.z * Wk[(kk+2)*D+ch];
            ak1 += xx.y * Wk[(kk+1)*D+ch] + xx.w * Wk[(kk+3)*D+ch];
            av0 += xx.x * Wv[(kk+0)*D+ch] + xx.z * Wv[(kk+2)*D+ch];
            av1 += xx.y * Wv[(kk+1)*D+ch] + xx.w * Wv[(kk+3)*D+ch];
        }
        ppA[w * 192 + ch] = aq0 + aq1;
        ppA[w * 192 + 64 + ch] = ak0 + ak1;
        ppA[w * 192 + 128 + ch] = av0 + av1;
        __syncthreads();
        if (kh == 0) {
            int head = ch >> 4, dh = ch & (DH - 1);
            size_t oidx = (((size_t)(b * NH + head)) * N + (q0 + tok4)) * DH + dh;
            qsh[tok4 * D + ch] = bq[ch] + ppA[tok4*192 + ch] + ppA[(tok4+4)*192 + ch];
            k0[oidx] = bk[ch] + ppA[tok4*192 + 64 + ch] + ppA[(tok4+4)*192 + 64 + ch];
            v0[oidx] = bv[ch] + ppA[tok4*192 + 128 + ch] + ppA[(tok4+4)*192 + 128 + ch];
        }
    }
    __threadfence();
    grid.sync();   // k0/v0 complete

    // ---- layer 0 (fuses layer-1 QKV: q->LDS, k1/v1->global) ----
    layer_body<true, false>(lane, w, b, q0, xv, k0, v0,
        Wo, bo, ln1g, ln1b, Wff1, bff1, Wff2, bff2, ln2g, ln2b,
        Wq + (size_t)D * D, bq + D, Wk + (size_t)D * D, bk + D,
        Wv + (size_t)D * D, bv + D, k1, v1,
        qsh, attS, xs, f1s, ppA, ppB, attO, attM, attL, xout);
    __threadfence();
    grid.sync();   // k1/v1 complete

    // ---- layer 1 (writes final x) ----
    layer_body<false, true>(lane, w, b, q0, xv, k1, v1,
        Wo + (size_t)D * D, bo + D, ln1g + D, ln1b + D,
        Wff1 + (size_t)D * 2 * D, bff1 + 2 * D,
        Wff2 + (size_t)2 * D * D, bff2 + D, ln2g + D, ln2b + D,
        nullptr, nullptr, nullptr, nullptr, nullptr, nullptr,
        nullptr, nullptr,
        qsh, attS, xs, f1s, ppA, ppB, attO, attM, attL, xout);
}

extern "C" void kernel_launch(void* const* d_in, const int* in_sizes, int n_in,
                              void* d_out, int out_size, void* d_ws, size_t ws_size,
                              hipStream_t stream) {
    const float* feature = (const float*)d_in[0];
    const float* W1   = (const float*)d_in[1];
    const float* b1   = (const float*)d_in[2];
    const float* mw   = (const float*)d_in[3];
    const float* mb   = (const float*)d_in[4];
    const float* bn_g = (const float*)d_in[5];
    const float* bn_b = (const float*)d_in[6];
    const float* Wq   = (const float*)d_in[7];
    const float* bq   = (const float*)d_in[8];
    const float* Wk   = (const float*)d_in[9];
    const float* bk   = (const float*)d_in[10];
    const float* Wv   = (const float*)d_in[11];
    const float* bv   = (const float*)d_in[12];
    const float* Wo   = (const float*)d_in[13];
    const float* bo   = (const float*)d_in[14];
    const float* ln1g = (const float*)d_in[15];
    const float* ln1b = (const float*)d_in[16];
    const float* Wff1 = (const float*)d_in[17];
    const float* bff1 = (const float*)d_in[18];
    const float* Wff2 = (const float*)d_in[19];
    const float* bff2 = (const float*)d_in[20];
    const float* ln2g = (const float*)d_in[21];
    const float* ln2b = (const float*)d_in[22];

    float* ws    = (float*)d_ws;
    float* rs    = ws;                     // B*N*NH = 4096
    float* bnacc = rs + B * N * NH;        // 128
    float* k0    = bnacc + 128;            // B*N*D each
    float* v0    = k0 + B * N * D;
    float* k1    = v0 + B * N * D;
    float* v1    = k1 + B * N * D;
    float* xout  = (float*)d_out;

    void* args[] = {
        (void*)&feature, (void*)&W1, (void*)&b1, (void*)&mw, (void*)&mb,
        (void*)&bn_g, (void*)&bn_b,
        (void*)&Wq, (void*)&bq, (void*)&Wk, (void*)&bk, (void*)&Wv, (void*)&bv,
        (void*)&Wo, (void*)&bo, (void*)&ln1g, (void*)&ln1b,
        (void*)&Wff1, (void*)&bff1, (void*)&Wff2, (void*)&bff2,
        (void*)&ln2g, (void*)&ln2b,
        (void*)&rs, (void*)&bnacc, (void*)&k0, (void*)&v0, (void*)&k1, (void*)&v1,
        (void*)&xout
    };
    hipLaunchCooperativeKernel((const void*)k_all, dim3(256), dim3(512),
                               args, 0, stream);
}

// Round 9
// 179.849 us; speedup vs baseline: 2.3290x; 2.3290x over previous
//
#include <hip/hip_runtime.h>
#include <math.h>

#define B 4
#define N 256
#define DIN 4
#define D 64
#define NH 4
#define NL 2
#define DH 16

constexpr float EPS = 1e-5f;
constexpr float SLOPE = 0.01f;

// ---------------------------------------------------------------------------
// D1: merged rowsum + aggregate + h-proj + BN partials. grid 256, block 512.
// Phase A: each block REDUNDANTLY computes its batch's full rs[256][4] into
// LDS (coalesced scan of the 1 MB batch slab, L2-resident after first touch)
// — this removes the rowsum dispatch and its ~18 us boundary.
// Phase B/C: R6's proven aggregate body, reading rs from LDS.
// bnacc must be zeroed by a preceding memset node (same-dispatch init races).
// ---------------------------------------------------------------------------
__global__ void __launch_bounds__(512) k_pre(
    const float* __restrict__ feature, const float* __restrict__ W1,
    const float* __restrict__ b1, const float* __restrict__ mw,
    const float* __restrict__ mb,
    float* __restrict__ h, float* __restrict__ bnacc) {
    __shared__ float rsL[N][4];    // full-batch rowsums (redundant per block)
    __shared__ float part2[8][10];
    __shared__ float gacc[20];
    __shared__ float hs[4][D];
    int t = threadIdx.x;
    int lane = t & 63, w = t >> 6;
    int cb = blockIdx.x;
    int b = cb >> 6, j0 = (cb & 63) * 4;

    // ---- M/C projection in registers (redundant per wave; proven R5/R6) ----
    float w1v[4];
#pragma unroll
    for (int kk = 0; kk < 4; ++kk) w1v[kk] = W1[kk * D + lane];
    float b1v = b1[lane];
    float Mreg[16], Creg[4];
#pragma unroll
    for (int n = 0; n < 4; ++n) {
        float mwv = mw[n * D + lane];
        float p0 = w1v[0] * mwv, p1 = w1v[1] * mwv;
        float p2 = w1v[2] * mwv, p3 = w1v[3] * mwv;
        float pc = b1v * mwv;
#pragma unroll
        for (int off = 32; off > 0; off >>= 1) {
            p0 += __shfl_xor(p0, off); p1 += __shfl_xor(p1, off);
            p2 += __shfl_xor(p2, off); p3 += __shfl_xor(p3, off);
            pc += __shfl_xor(pc, off);
        }
        Mreg[n * 4 + 0] = p0; Mreg[n * 4 + 1] = p1;
        Mreg[n * 4 + 2] = p2; Mreg[n * 4 + 3] = p3;
        Creg[n] = pc + mb[n];
    }

    // ---- Phase A: full-batch rowsum -> rsL. wave w owns rows w, w+8, ... ----
    {
        const float4* fbase = (const float4*)feature + (size_t)b * N * N;
#pragma unroll 4
        for (int r = 0; r < 32; ++r) {
            int i = w + 8 * r;
            const float4* frow = fbase + (size_t)i * N;
            float sn[4] = {0.f, 0.f, 0.f, 0.f};
#pragma unroll
            for (int m = 0; m < 4; ++m) {
                float4 f = frow[64 * m + lane];
#pragma unroll
                for (int n = 0; n < 4; ++n) {
                    float s = Creg[n] + f.x * Mreg[n*4+0] + f.y * Mreg[n*4+1]
                                      + f.z * Mreg[n*4+2] + f.w * Mreg[n*4+3];
                    s = (s >= 0.f) ? s : SLOPE * s;
                    sn[n] += __expf(s);
                }
            }
#pragma unroll
            for (int n = 0; n < 4; ++n)
#pragma unroll
                for (int off = 32; off > 0; off >>= 1) sn[n] += __shfl_xor(sn[n], off);
            if (lane < 4) rsL[i][lane] = (lane == 0) ? sn[0] :
                                         (lane == 1) ? sn[1] :
                                         (lane == 2) ? sn[2] : sn[3];
        }
    }
    __syncthreads();

    // ---- Phase B: aggregate (R6 body; rs from LDS) ----
    int i = t & 255, jh = t >> 8;
    const float4* fb2 = (const float4*)feature + ((size_t)(b * N + i) * N + j0 + jh * 2);
    float4 f[2];
    f[0] = fb2[0];
    f[1] = fb2[1];
    float4 r4 = *(const float4*)&rsL[i][0];
    float rinv[4] = {1.f / r4.x, 1.f / r4.y, 1.f / r4.z, 1.f / r4.w};
    float acc[2][5];
#pragma unroll
    for (int jj = 0; jj < 2; ++jj) {
        float wbar = 0.f;
#pragma unroll
        for (int n = 0; n < 4; ++n) {
            float s = Creg[n] + f[jj].x * Mreg[n*4+0] + f[jj].y * Mreg[n*4+1]
                              + f[jj].z * Mreg[n*4+2] + f[jj].w * Mreg[n*4+3];
            s = (s >= 0.f) ? s : SLOPE * s;
            wbar += __expf(s) * rinv[n];
        }
        wbar *= 0.25f;
        acc[jj][0] = wbar * f[jj].x; acc[jj][1] = wbar * f[jj].y;
        acc[jj][2] = wbar * f[jj].z; acc[jj][3] = wbar * f[jj].w;
        acc[jj][4] = wbar;
    }
#pragma unroll
    for (int jj = 0; jj < 2; ++jj)
#pragma unroll
        for (int c = 0; c < 5; ++c)
#pragma unroll
            for (int off = 32; off > 0; off >>= 1) acc[jj][c] += __shfl_xor(acc[jj][c], off);
    if (lane == 0) {
#pragma unroll
        for (int jj = 0; jj < 2; ++jj)
#pragma unroll
            for (int c = 0; c < 5; ++c) part2[w][jj * 5 + c] = acc[jj][c];
    }
    __syncthreads();
    if (t < 20) {
        int jj = t / 5, c = t - jj * 5;
        int g = jj >> 1, jjl = jj & 1;
        gacc[t] = part2[g*4+0][jjl*5+c] + part2[g*4+1][jjl*5+c]
                + part2[g*4+2][jjl*5+c] + part2[g*4+3][jjl*5+c];
    }
    __syncthreads();
    if (t < 256) {   // wave w = token j0+w, lane = channel
        float hv = gacc[w * 5 + 4] * b1v;
#pragma unroll
        for (int kk = 0; kk < 4; ++kk) hv += gacc[w * 5 + kk] * w1v[kk];
        h[((size_t)(b * N + j0 + w)) * D + lane] = hv;
        hs[w][lane] = hv;
    }
    __syncthreads();
    if (t < 64) {
        float s = hs[0][lane] + hs[1][lane] + hs[2][lane] + hs[3][lane];
        float sq = hs[0][lane]*hs[0][lane] + hs[1][lane]*hs[1][lane]
                 + hs[2][lane]*hs[2][lane] + hs[3][lane]*hs[3][lane];
        atomicAdd(bnacc + lane, s);
        atomicAdd(bnacc + D + lane, sq);
    }
}

// ---------------------------------------------------------------------------
// D2: BN finalize + QKV layer 0 (R6 body, unchanged). grid (B, N/2) x 256.
// ---------------------------------------------------------------------------
__global__ void __launch_bounds__(256, 2) k_qkv0(
    const float* __restrict__ h, const float* __restrict__ bnacc,
    const float* __restrict__ bn_g, const float* __restrict__ bn_b,
    const float* __restrict__ Wq, const float* __restrict__ bq,
    const float* __restrict__ Wk, const float* __restrict__ bk,
    const float* __restrict__ Wv, const float* __restrict__ bv,
    float* __restrict__ x, float* __restrict__ q,
    float* __restrict__ k, float* __restrict__ v) {
    __shared__ float xs[2][D];
    __shared__ float pp[4][2][192];
    int t = threadIdx.x, lane = t & 63, w = t >> 6, ch = lane;
    int b = blockIdx.x, n0 = blockIdx.y * 2;

    float wq[16], wk[16], wv[16];
#pragma unroll
    for (int i = 0; i < 16; ++i) {
        int kk = w * 16 + i;
        wq[i] = Wq[kk * D + ch];
        wk[i] = Wk[kk * D + ch];
        wv[i] = Wv[kk * D + ch];
    }
    float mean = bnacc[ch] * (1.0f / (B * N));
    float var = bnacc[D + ch] * (1.0f / (B * N)) - mean * mean;
    float inv = rsqrtf(var + EPS);
    size_t xi0 = ((size_t)(b * N + n0)) * D + ch;
    float xv0 = bn_g[ch] * (h[xi0] - mean) * inv + bn_b[ch];
    float xv1 = bn_g[ch] * (h[xi0 + D] - mean) * inv + bn_b[ch];
    if (w == 0) { x[xi0] = xv0; xs[0][ch] = xv0; }
    if (w == 1) { x[xi0 + D] = xv1; xs[1][ch] = xv1; }
    __syncthreads();

    float aq0=0.f, ak0=0.f, av0=0.f, aq1=0.f, ak1=0.f, av1=0.f;
#pragma unroll
    for (int i = 0; i < 16; ++i) {
        int kk = w * 16 + i;
        float xx0 = xs[0][kk], xx1 = xs[1][kk];
        aq0 += xx0 * wq[i]; ak0 += xx0 * wk[i]; av0 += xx0 * wv[i];
        aq1 += xx1 * wq[i]; ak1 += xx1 * wk[i]; av1 += xx1 * wv[i];
    }
    pp[w][0][ch] = aq0; pp[w][0][64 + ch] = ak0; pp[w][0][128 + ch] = av0;
    pp[w][1][ch] = aq1; pp[w][1][64 + ch] = ak1; pp[w][1][128 + ch] = av1;
    __syncthreads();
    if (w < 3) {
        int o = w * 64;
        int head = ch >> 4, dh = ch & (DH - 1);
#pragma unroll
        for (int tk = 0; tk < 2; ++tk) {
            float val = pp[0][tk][o+ch] + pp[1][tk][o+ch] + pp[2][tk][o+ch] + pp[3][tk][o+ch];
            size_t oidx = (((size_t)(b * NH + head)) * N + (n0 + tk)) * DH + dh;
            if (w == 0) q[oidx] = val + bq[ch];
            else if (w == 1) k[oidx] = val + bk[ch];
            else v[oidx] = val + bv[ch];
        }
    }
}

// ---------------------------------------------------------------------------
// D3/D4: layer tail (R6 body, unchanged). grid (B, N/2) x 256.
// ---------------------------------------------------------------------------
template <bool FUSE>
__global__ void __launch_bounds__(256, 2) k_layer(
    const float* __restrict__ q, const float* __restrict__ k,
    const float* __restrict__ v,
    const float* __restrict__ Wo, const float* __restrict__ bo,
    const float* __restrict__ ln1g, const float* __restrict__ ln1b,
    const float* __restrict__ Wff1, const float* __restrict__ bff1,
    const float* __restrict__ Wff2, const float* __restrict__ bff2,
    const float* __restrict__ ln2g, const float* __restrict__ ln2b,
    const float* __restrict__ Wqn, const float* __restrict__ bqn,
    const float* __restrict__ Wkn, const float* __restrict__ bkn,
    const float* __restrict__ Wvn, const float* __restrict__ bvn,
    float* __restrict__ qo, float* __restrict__ ko, float* __restrict__ vo,
    float* __restrict__ x) {
    __shared__ float attS[2][D];
    __shared__ float xs[2][D];
    __shared__ float f1s[2][2 * D];
    __shared__ float ppA[4][2][192];
    __shared__ float ppB[4][2][192];
    int t = threadIdx.x, lane = t & 63, w = t >> 6, ch = lane;
    int b = blockIdx.x, n0 = blockIdx.y * 2;

    size_t xi0 = ((size_t)(b * N + n0)) * D + ch;
    float xv0 = x[xi0], xv1 = x[xi0 + D];
    float bo_r = bo[ch], l1g = ln1g[ch], l1b = ln1b[ch];
    float bf1a = bff1[ch], bf1b = bff1[D + ch];
    float bf2_r = bff2[ch], l2g = ln2g[ch], l2b = ln2b[ch];

    // ---- attention: wave = head; stream K/V in 4 chunks of 64 keys ----
    int bh = b * NH + w;
    const float4* qp0 = (const float4*)(q + ((size_t)bh * N + n0) * DH);
    const float4* qp1 = (const float4*)(q + ((size_t)bh * N + n0 + 1) * DH);
    float4 qv0[4], qv1[4];
#pragma unroll
    for (int c = 0; c < 4; ++c) { qv0[c] = qp0[c]; qv1[c] = qp1[c]; }
    const float* kb = k + (size_t)bh * N * DH;
    const float* vb = v + (size_t)bh * N * DH;
    float o0[DH], o1[DH];
#pragma unroll
    for (int d = 0; d < DH; ++d) { o0[d] = 0.f; o1[d] = 0.f; }
    float l0 = 0.f, l1 = 0.f;
#pragma unroll 1
    for (int cc = 0; cc < 4; ++cc) {
        int key = cc * 64 + lane;
        const float4* kp4 = (const float4*)(kb + (size_t)key * DH);
        const float4* vp4 = (const float4*)(vb + (size_t)key * DH);
        float4 Kc[4], Vc[4];
#pragma unroll
        for (int c = 0; c < 4; ++c) { Kc[c] = kp4[c]; Vc[c] = vp4[c]; }
        float s0 = 0.f, s1 = 0.f;
#pragma unroll
        for (int c = 0; c < 4; ++c) {
            s0 += qv0[c].x * Kc[c].x + qv0[c].y * Kc[c].y +
                  qv0[c].z * Kc[c].z + qv0[c].w * Kc[c].w;
            s1 += qv1[c].x * Kc[c].x + qv1[c].y * Kc[c].y +
                  qv1[c].z * Kc[c].z + qv1[c].w * Kc[c].w;
        }
        float p0 = __expf(s0 * 0.25f);
        float p1 = __expf(s1 * 0.25f);
        l0 += p0; l1 += p1;
#pragma unroll
        for (int c = 0; c < 4; ++c) {
            o0[4*c+0] += p0 * Vc[c].x; o0[4*c+1] += p0 * Vc[c].y;
            o0[4*c+2] += p0 * Vc[c].z; o0[4*c+3] += p0 * Vc[c].w;
            o1[4*c+0] += p1 * Vc[c].x; o1[4*c+1] += p1 * Vc[c].y;
            o1[4*c+2] += p1 * Vc[c].z; o1[4*c+3] += p1 * Vc[c].w;
        }
    }
    float wo[16];
#pragma unroll
    for (int i = 0; i < 16; ++i) wo[i] = Wo[(w * 16 + i) * D + ch];

#pragma unroll
    for (int off = 32; off > 0; off >>= 1) {
        l0 += __shfl_xor(l0, off);
        l1 += __shfl_xor(l1, off);
    }
#pragma unroll
    for (int d = 0; d < DH; ++d) {
#pragma unroll
        for (int off = 32; off > 0; off >>= 1) {
            o0[d] += __shfl_xor(o0[d], off);
            o1[d] += __shfl_xor(o1[d], off);
        }
    }
    float rl0 = 1.f / l0, rl1 = 1.f / l1;
    if (lane < DH) {
        float sel0 = o0[0], sel1 = o1[0];
#pragma unroll
        for (int d = 1; d < DH; ++d)
            if (lane == d) { sel0 = o0[d]; sel1 = o1[d]; }
        attS[0][w * DH + lane] = sel0 * rl0;
        attS[1][w * DH + lane] = sel1 * rl1;
    }
    __syncthreads();

    // ---- O-proj (split-K-4, both tokens) + prefetch Wff1 ----
    {
        float a0 = 0.f, a1 = 0.f;
#pragma unroll
        for (int i = 0; i < 16; ++i) {
            int kk = w * 16 + i;
            float wv = wo[i];
            a0 += attS[0][kk] * wv;
            a1 += attS[1][kk] * wv;
        }
        ppA[w][0][ch] = a0; ppA[w][1][ch] = a1;
    }
    float wf1a[16], wf1b[16];
#pragma unroll
    for (int i = 0; i < 16; ++i) {
        int kk = w * 16 + i;
        wf1a[i] = Wff1[kk * 2 * D + ch];
        wf1b[i] = Wff1[kk * 2 * D + D + ch];
    }
    __syncthreads();

    // ---- LN1 (both tokens, redundant per wave) ----
    float r0 = xv0 + bo_r + ppA[0][0][ch] + ppA[1][0][ch] + ppA[2][0][ch] + ppA[3][0][ch];
    float r1 = xv1 + bo_r + ppA[0][1][ch] + ppA[1][1][ch] + ppA[2][1][ch] + ppA[3][1][ch];
    float s0a = r0, q0a = r0 * r0, s1a = r1, q1a = r1 * r1;
#pragma unroll
    for (int off = 32; off > 0; off >>= 1) {
        s0a += __shfl_xor(s0a, off); q0a += __shfl_xor(q0a, off);
        s1a += __shfl_xor(s1a, off); q1a += __shfl_xor(q1a, off);
    }
    float mean10 = s0a * (1.0f / D), var10 = q0a * (1.0f / D) - mean10 * mean10;
    float mean11 = s1a * (1.0f / D), var11 = q1a * (1.0f / D) - mean11 * mean11;
    float x1_0 = l1g * (r0 - mean10) * rsqrtf(var10 + EPS) + l1b;
    float x1_1 = l1g * (r1 - mean11) * rsqrtf(var11 + EPS) + l1b;
    if (w == 0) xs[0][ch] = x1_0;
    if (w == 1) xs[1][ch] = x1_1;
    __syncthreads();

    // ---- FFN1 (split-K-4, both halves, both tokens) + prefetch Wff2 ----
    {
        float u0=0.f, g0=0.f, u1=0.f, g1=0.f;
#pragma unroll
        for (int i = 0; i < 16; ++i) {
            int kk = w * 16 + i;
            float xx0 = xs[0][kk], xx1 = xs[1][kk];
            u0 += xx0 * wf1a[i]; g0 += xx0 * wf1b[i];
            u1 += xx1 * wf1a[i]; g1 += xx1 * wf1b[i];
        }
        ppB[w][0][ch] = u0; ppB[w][0][64 + ch] = g0;
        ppB[w][1][ch] = u1; ppB[w][1][64 + ch] = g1;
    }
    float wf2[32];
#pragma unroll
    for (int i = 0; i < 32; ++i) wf2[i] = Wff2[(w * 32 + i) * D + ch];
    __syncthreads();

    // ---- ReLU combine -> f1s ----
    {
        float a00 = fmaxf(bf1a + ppB[0][0][ch] + ppB[1][0][ch] + ppB[2][0][ch] + ppB[3][0][ch], 0.f);
        float a01 = fmaxf(bf1b + ppB[0][0][64+ch] + ppB[1][0][64+ch] + ppB[2][0][64+ch] + ppB[3][0][64+ch], 0.f);
        float a10 = fmaxf(bf1a + ppB[0][1][ch] + ppB[1][1][ch] + ppB[2][1][ch] + ppB[3][1][ch], 0.f);
        float a11 = fmaxf(bf1b + ppB[0][1][64+ch] + ppB[1][1][64+ch] + ppB[2][1][64+ch] + ppB[3][1][64+ch], 0.f);
        if (w == 0) { f1s[0][ch] = a00; f1s[0][64 + ch] = a01; }
        if (w == 1) { f1s[1][ch] = a10; f1s[1][64 + ch] = a11; }
    }
    __syncthreads();

    // ---- FFN2 (split-K-4 over 128, both tokens) + prefetch next QKV ----
    {
        float e0 = 0.f, e1 = 0.f;
#pragma unroll
        for (int i = 0; i < 32; ++i) {
            int kk = w * 32 + i;
            float xx0 = f1s[0][kk], xx1 = f1s[1][kk];
            e0 += xx0 * wf2[i];
            e1 += xx1 * wf2[i];
        }
        ppA[w][0][ch] = e0; ppA[w][1][ch] = e1;
    }
    float wqn[16], wkn[16], wvn[16];
    if (FUSE) {
#pragma unroll
        for (int i = 0; i < 16; ++i) {
            int kk = w * 16 + i;
            wqn[i] = Wqn[kk * D + ch];
            wkn[i] = Wkn[kk * D + ch];
            wvn[i] = Wvn[kk * D + ch];
        }
    }
    __syncthreads();

    // ---- LN2 (both tokens, redundant per wave) ----
    float o2_0 = bf2_r + ppA[0][0][ch] + ppA[1][0][ch] + ppA[2][0][ch] + ppA[3][0][ch];
    float o2_1 = bf2_r + ppA[0][1][ch] + ppA[1][1][ch] + ppA[2][1][ch] + ppA[3][1][ch];
    float r20 = x1_0 + o2_0, r21 = x1_1 + o2_1;
    float s0b = r20, q0b = r20 * r20, s1b = r21, q1b = r21 * r21;
#pragma unroll
    for (int off = 32; off > 0; off >>= 1) {
        s0b += __shfl_xor(s0b, off); q0b += __shfl_xor(q0b, off);
        s1b += __shfl_xor(s1b, off); q1b += __shfl_xor(q1b, off);
    }
    float mean20 = s0b * (1.0f / D), var20 = q0b * (1.0f / D) - mean20 * mean20;
    float mean21 = s1b * (1.0f / D), var21 = q1b * (1.0f / D) - mean21 * mean21;
    float xn0 = l2g * (r20 - mean20) * rsqrtf(var20 + EPS) + l2b;
    float xn1 = l2g * (r21 - mean21) * rsqrtf(var21 + EPS) + l2b;
    if (w == 0) x[xi0] = xn0;
    if (w == 1) x[xi0 + D] = xn1;

    // ---- fused next-layer QKV ----
    if (FUSE) {
        if (w == 0) xs[0][ch] = xn0;
        if (w == 1) xs[1][ch] = xn1;
        __syncthreads();
        float aq0=0.f, ak0=0.f, av0=0.f, aq1=0.f, ak1=0.f, av1=0.f;
#pragma unroll
        for (int i = 0; i < 16; ++i) {
            int kk = w * 16 + i;
            float xx0 = xs[0][kk], xx1 = xs[1][kk];
            aq0 += xx0 * wqn[i]; ak0 += xx0 * wkn[i]; av0 += xx0 * wvn[i];
            aq1 += xx1 * wqn[i]; ak1 += xx1 * wkn[i]; av1 += xx1 * wvn[i];
        }
        ppB[w][0][ch] = aq0; ppB[w][0][64 + ch] = ak0; ppB[w][0][128 + ch] = av0;
        ppB[w][1][ch] = aq1; ppB[w][1][64 + ch] = ak1; ppB[w][1][128 + ch] = av1;
        __syncthreads();
        if (w < 3) {
            int o = w * 64;
            int head = ch >> 4, dh = ch & (DH - 1);
#pragma unroll
            for (int tk = 0; tk < 2; ++tk) {
                float val = ppB[0][tk][o+ch] + ppB[1][tk][o+ch] + ppB[2][tk][o+ch] + ppB[3][tk][o+ch];
                size_t oidx = (((size_t)(b * NH + head)) * N + (n0 + tk)) * DH + dh;
                if (w == 0) qo[oidx] = val + bqn[ch];
                else if (w == 1) ko[oidx] = val + bkn[ch];
                else vo[oidx] = val + bvn[ch];
            }
        }
    }
}

extern "C" void kernel_launch(void* const* d_in, const int* in_sizes, int n_in,
                              void* d_out, int out_size, void* d_ws, size_t ws_size,
                              hipStream_t stream) {
    const float* feature = (const float*)d_in[0];
    const float* W1   = (const float*)d_in[1];
    const float* b1   = (const float*)d_in[2];
    const float* mw   = (const float*)d_in[3];
    const float* mb   = (const float*)d_in[4];
    const float* bn_g = (const float*)d_in[5];
    const float* bn_b = (const float*)d_in[6];
    const float* Wq   = (const float*)d_in[7];
    const float* bq   = (const float*)d_in[8];
    const float* Wk   = (const float*)d_in[9];
    const float* bk   = (const float*)d_in[10];
    const float* Wv   = (const float*)d_in[11];
    const float* bv   = (const float*)d_in[12];
    const float* Wo   = (const float*)d_in[13];
    const float* bo   = (const float*)d_in[14];
    const float* ln1g = (const float*)d_in[15];
    const float* ln1b = (const float*)d_in[16];
    const float* Wff1 = (const float*)d_in[17];
    const float* bff1 = (const float*)d_in[18];
    const float* Wff2 = (const float*)d_in[19];
    const float* bff2 = (const float*)d_in[20];
    const float* ln2g = (const float*)d_in[21];
    const float* ln2b = (const float*)d_in[22];

    float* ws    = (float*)d_ws;
    float* bnacc = ws;                     // 128
    float* h     = bnacc + 128;            // B*N*D
    float* q     = h + B * N * D;          // B*N*D
    float* k0    = q + B * N * D;
    float* v0    = k0 + B * N * D;
    float* k1    = v0 + B * N * D;
    float* v1    = k1 + B * N * D;
    float* x     = (float*)d_out;          // running (B,N,D) activation

    hipMemsetAsync(bnacc, 0, 128 * sizeof(float), stream);
    k_pre<<<256, 512, 0, stream>>>(feature, W1, b1, mw, mb, h, bnacc);
    k_qkv0<<<dim3(B, N / 2), 256, 0, stream>>>(h, bnacc, bn_g, bn_b,
                                               Wq, bq, Wk, bk, Wv, bv, x, q, k0, v0);
    // layer 0 (fused layer-1 QKV into q / k1 / v1), then layer 1
    k_layer<true><<<dim3(B, N / 2), 256, 0, stream>>>(q, k0, v0,
        Wo, bo, ln1g, ln1b, Wff1, bff1, Wff2, bff2, ln2g, ln2b,
        Wq + (size_t)D * D, bq + D, Wk + (size_t)D * D, bk + D,
        Wv + (size_t)D * D, bv + D, q, k1, v1, x);
    k_layer<false><<<dim3(B, N / 2), 256, 0, stream>>>(q, k1, v1,
        Wo + (size_t)D * D, bo + D, ln1g + D, ln1b + D,
        Wff1 + (size_t)D * 2 * D, bff1 + 2 * D,
        Wff2 + (size_t)2 * D * D, bff2 + D, ln2g + D, ln2b + D,
        nullptr, nullptr, nullptr, nullptr, nullptr, nullptr,
        nullptr, nullptr, nullptr, x);
}

// Round 10
// 142.834 us; speedup vs baseline: 2.9325x; 1.2591x over previous
//
#include <hip/hip_runtime.h>
#include <math.h>

#define B 4
#define N 256
#define DIN 4
#define D 64
#define NH 4
#define NL 2
#define DH 16

constexpr float EPS = 1e-5f;
constexpr float SLOPE = 0.01f;

// ---------------------------------------------------------------------------
// Register M/C projection: M[n][k] = sum_d W1[k][d]*mw[n][d]; C[n] = mb[n] +
// sum_d b1[d]*mw[n][d]. Computed redundantly per wave via butterfly reduce.
// ---------------------------------------------------------------------------
__device__ __forceinline__ void mc_proj(
    const float* __restrict__ W1, const float* __restrict__ b1,
    const float* __restrict__ mw, const float* __restrict__ mb,
    int lane, float* Mreg /*16*/, float* Creg /*4*/) {
    float w1v[4];
#pragma unroll
    for (int kk = 0; kk < 4; ++kk) w1v[kk] = W1[kk * D + lane];
    float b1v = b1[lane];
#pragma unroll
    for (int n = 0; n < 4; ++n) {
        float mwv = mw[n * D + lane];
        float p0 = w1v[0] * mwv, p1 = w1v[1] * mwv;
        float p2 = w1v[2] * mwv, p3 = w1v[3] * mwv;
        float pc = b1v * mwv;
#pragma unroll
        for (int off = 32; off > 0; off >>= 1) {
            p0 += __shfl_xor(p0, off); p1 += __shfl_xor(p1, off);
            p2 += __shfl_xor(p2, off); p3 += __shfl_xor(p3, off);
            pc += __shfl_xor(pc, off);
        }
        Mreg[n * 4 + 0] = p0; Mreg[n * 4 + 1] = p1;
        Mreg[n * 4 + 2] = p2; Mreg[n * 4 + 3] = p3;
        Creg[n] = pc + mb[n];
    }
}

// ---------------------------------------------------------------------------
// P1: rowsum. grid 256, block 512 (8 waves). Wave w = (row r=w&3, half mh).
// ---------------------------------------------------------------------------
__global__ void __launch_bounds__(512) k_rowsum(
    const float* __restrict__ feature, const float* __restrict__ W1,
    const float* __restrict__ b1, const float* __restrict__ mw,
    const float* __restrict__ mb, float* __restrict__ rs,
    float* __restrict__ bnacc /* [128]: macc|sacc */) {
    __shared__ float part[32];   // [8 waves][4 heads]
    int t = threadIdx.x;
    int lane = t & 63, w = t >> 6;
    int cb = blockIdx.x;
    if (cb == 0 && t < 128) bnacc[t] = 0.f;

    int r = w & 3, mh = w >> 2;
    int bi = cb * 4 + r;
    const float4* fb = (const float4*)(feature) + (size_t)bi * N;
    float4 f0 = fb[lane + 64 * (mh * 2 + 0)];
    float4 f1 = fb[lane + 64 * (mh * 2 + 1)];

    float Mreg[16], Creg[4];
    mc_proj(W1, b1, mw, mb, lane, Mreg, Creg);

    float sn[4] = {0.f, 0.f, 0.f, 0.f};
#pragma unroll
    for (int mm = 0; mm < 2; ++mm) {
        float4 f = (mm == 0) ? f0 : f1;
#pragma unroll
        for (int n = 0; n < 4; ++n) {
            float s = Creg[n] + f.x * Mreg[n*4+0] + f.y * Mreg[n*4+1]
                              + f.z * Mreg[n*4+2] + f.w * Mreg[n*4+3];
            s = (s >= 0.f) ? s : SLOPE * s;
            sn[n] += __expf(s);
        }
    }
#pragma unroll
    for (int n = 0; n < 4; ++n)
#pragma unroll
        for (int off = 32; off > 0; off >>= 1) sn[n] += __shfl_xor(sn[n], off);
    if (lane == 0) {
#pragma unroll
        for (int n = 0; n < 4; ++n) part[w * 4 + n] = sn[n];
    }
    __syncthreads();
    if (t < 16) {
        int rr = t >> 2, n = t & 3;
        rs[((size_t)(cb * 4 + rr)) * 4 + n] = part[rr * 4 + n] + part[(rr + 4) * 4 + n];
    }
}

// ---------------------------------------------------------------------------
// P2: aggregate + h projection + BN partial sums. grid 256, block 512.
// Thread = (i = t&255, j-half jh = t>>8); each thread handles 2 j's.
// ---------------------------------------------------------------------------
__global__ void __launch_bounds__(512) k_aggregate(
    const float* __restrict__ feature, const float* __restrict__ W1,
    const float* __restrict__ b1, const float* __restrict__ mw,
    const float* __restrict__ mb, const float* __restrict__ rs,
    float* __restrict__ h, float* __restrict__ bnacc) {
    __shared__ float part[8][10];  // [wave][jjl*5+c]
    __shared__ float gacc[20];     // [jj][c]
    __shared__ float hs[4][D];
    int t = threadIdx.x;
    int lane = t & 63, w = t >> 6;
    int cb = blockIdx.x;

    int b = cb >> 6, j0 = (cb & 63) * 4;
    int i = t & 255, jh = t >> 8;
    const float4* fb = (const float4*)(feature) + ((size_t)(b * N + i) * N + j0 + jh * 2);
    float4 f[2];
    f[0] = fb[0];
    f[1] = fb[1];
    float4 r4 = *(const float4*)(rs + (size_t)(b * N + i) * 4);

    float Mreg[16], Creg[4];
    mc_proj(W1, b1, mw, mb, lane, Mreg, Creg);
    float w1v[4];
#pragma unroll
    for (int kk = 0; kk < 4; ++kk) w1v[kk] = W1[kk * D + lane];
    float b1v = b1[lane];

    float rinv[4] = {1.f / r4.x, 1.f / r4.y, 1.f / r4.z, 1.f / r4.w};
    float acc[2][5];
#pragma unroll
    for (int jj = 0; jj < 2; ++jj) {
        float wbar = 0.f;
#pragma unroll
        for (int n = 0; n < 4; ++n) {
            float s = Creg[n] + f[jj].x * Mreg[n*4+0] + f[jj].y * Mreg[n*4+1]
                              + f[jj].z * Mreg[n*4+2] + f[jj].w * Mreg[n*4+3];
            s = (s >= 0.f) ? s : SLOPE * s;
            wbar += __expf(s) * rinv[n];
        }
        wbar *= 0.25f;
        acc[jj][0] = wbar * f[jj].x; acc[jj][1] = wbar * f[jj].y;
        acc[jj][2] = wbar * f[jj].z; acc[jj][3] = wbar * f[jj].w;
        acc[jj][4] = wbar;
    }
#pragma unroll
    for (int jj = 0; jj < 2; ++jj)
#pragma unroll
        for (int c = 0; c < 5; ++c)
#pragma unroll
            for (int off = 32; off > 0; off >>= 1) acc[jj][c] += __shfl_xor(acc[jj][c], off);
    if (lane == 0) {
#pragma unroll
        for (int jj = 0; jj < 2; ++jj)
#pragma unroll
            for (int c = 0; c < 5; ++c) part[w][jj * 5 + c] = acc[jj][c];
    }
    __syncthreads();
    if (t < 20) {
        int jj = t / 5, c = t - jj * 5;
        int g = jj >> 1, jjl = jj & 1;
        gacc[t] = part[g*4+0][jjl*5+c] + part[g*4+1][jjl*5+c]
                + part[g*4+2][jjl*5+c] + part[g*4+3][jjl*5+c];
    }
    __syncthreads();
    if (t < 256) {   // wave w = token j0+w, lane = channel
        float hv = gacc[w * 5 + 4] * b1v;
#pragma unroll
        for (int kk = 0; kk < 4; ++kk) hv += gacc[w * 5 + kk] * w1v[kk];
        h[((size_t)(b * N + j0 + w)) * D + lane] = hv;
        hs[w][lane] = hv;
    }
    __syncthreads();
    if (t < 64) {
        float s = hs[0][lane] + hs[1][lane] + hs[2][lane] + hs[3][lane];
        float sq = hs[0][lane]*hs[0][lane] + hs[1][lane]*hs[1][lane]
                 + hs[2][lane]*hs[2][lane] + hs[3][lane]*hs[3][lane];
        atomicAdd(bnacc + lane, s);
        atomicAdd(bnacc + D + lane, sq);
    }
}

// ---------------------------------------------------------------------------
// P3: BN finalize + QKV layer 0 (R6 body, unchanged). grid (B, N/2) x 256.
// ---------------------------------------------------------------------------
__global__ void __launch_bounds__(256, 2) k_qkv0(
    const float* __restrict__ h, const float* __restrict__ bnacc,
    const float* __restrict__ bn_g, const float* __restrict__ bn_b,
    const float* __restrict__ Wq, const float* __restrict__ bq,
    const float* __restrict__ Wk, const float* __restrict__ bk,
    const float* __restrict__ Wv, const float* __restrict__ bv,
    float* __restrict__ x, float* __restrict__ q,
    float* __restrict__ k, float* __restrict__ v) {
    __shared__ float xs[2][D];
    __shared__ float pp[4][2][192];
    int t = threadIdx.x, lane = t & 63, w = t >> 6, ch = lane;
    int b = blockIdx.x, n0 = blockIdx.y * 2;

    float wq[16], wk[16], wv[16];
#pragma unroll
    for (int i = 0; i < 16; ++i) {
        int kk = w * 16 + i;
        wq[i] = Wq[kk * D + ch];
        wk[i] = Wk[kk * D + ch];
        wv[i] = Wv[kk * D + ch];
    }
    float mean = bnacc[ch] * (1.0f / (B * N));
    float var = bnacc[D + ch] * (1.0f / (B * N)) - mean * mean;
    float inv = rsqrtf(var + EPS);
    size_t xi0 = ((size_t)(b * N + n0)) * D + ch;
    float xv0 = bn_g[ch] * (h[xi0] - mean) * inv + bn_b[ch];
    float xv1 = bn_g[ch] * (h[xi0 + D] - mean) * inv + bn_b[ch];
    if (w == 0) { x[xi0] = xv0; xs[0][ch] = xv0; }
    if (w == 1) { x[xi0 + D] = xv1; xs[1][ch] = xv1; }
    __syncthreads();

    float aq0=0.f, ak0=0.f, av0=0.f, aq1=0.f, ak1=0.f, av1=0.f;
#pragma unroll
    for (int i = 0; i < 16; ++i) {
        int kk = w * 16 + i;
        float xx0 = xs[0][kk], xx1 = xs[1][kk];
        aq0 += xx0 * wq[i]; ak0 += xx0 * wk[i]; av0 += xx0 * wv[i];
        aq1 += xx1 * wq[i]; ak1 += xx1 * wk[i]; av1 += xx1 * wv[i];
    }
    pp[w][0][ch] = aq0; pp[w][0][64 + ch] = ak0; pp[w][0][128 + ch] = av0;
    pp[w][1][ch] = aq1; pp[w][1][64 + ch] = ak1; pp[w][1][128 + ch] = av1;
    __syncthreads();
    if (w < 3) {
        int o = w * 64;
        int head = ch >> 4, dh = ch & (DH - 1);
#pragma unroll
        for (int tk = 0; tk < 2; ++tk) {
            float val = pp[0][tk][o+ch] + pp[1][tk][o+ch] + pp[2][tk][o+ch] + pp[3][tk][o+ch];
            size_t oidx = (((size_t)(b * NH + head)) * N + (n0 + tk)) * DH + dh;
            if (w == 0) q[oidx] = val + bq[ch];
            else if (w == 1) k[oidx] = val + bk[ch];
            else v[oidx] = val + bv[ch];
        }
    }
}

// Per-chunk attention compute on statically-named K/V buffers.
#define ATT_CHUNK(Kx, Vx)                                                      \
    {                                                                          \
        float s0 = 0.f, s1 = 0.f;                                              \
        _Pragma("unroll")                                                      \
        for (int c = 0; c < 4; ++c) {                                          \
            s0 += qv0[c].x * Kx[c].x + qv0[c].y * Kx[c].y +                    \
                  qv0[c].z * Kx[c].z + qv0[c].w * Kx[c].w;                     \
            s1 += qv1[c].x * Kx[c].x + qv1[c].y * Kx[c].y +                    \
                  qv1[c].z * Kx[c].z + qv1[c].w * Kx[c].w;                     \
        }                                                                      \
        float p0 = __expf(s0 * 0.25f);                                         \
        float p1 = __expf(s1 * 0.25f);                                         \
        l0 += p0; l1 += p1;                                                    \
        _Pragma("unroll")                                                      \
        for (int c = 0; c < 4; ++c) {                                          \
            o0[4*c+0] += p0 * Vx[c].x; o0[4*c+1] += p0 * Vx[c].y;              \
            o0[4*c+2] += p0 * Vx[c].z; o0[4*c+3] += p0 * Vx[c].w;              \
            o1[4*c+0] += p1 * Vx[c].x; o1[4*c+1] += p1 * Vx[c].y;              \
            o1[4*c+2] += p1 * Vx[c].z; o1[4*c+3] += p1 * Vx[c].w;              \
        }                                                                      \
    }

#define ATT_LOAD(Kx, Vx, cc)                                                   \
    {                                                                          \
        const float4* kp4 = (const float4*)(kb + (size_t)((cc) * 64 + lane) * DH); \
        const float4* vp4 = (const float4*)(vb + (size_t)((cc) * 64 + lane) * DH); \
        _Pragma("unroll")                                                      \
        for (int c = 0; c < 4; ++c) { Kx[c] = kp4[c]; Vx[c] = vp4[c]; }        \
    }

// ---------------------------------------------------------------------------
// D3/D4: layer tail (R6 body), with the K/V stream software-pipelined as a
// 2-deep register double-buffer (KA/VA, KB/VB — static names, no runtime
// indexing) so chunk n+1's loads overlap chunk n's compute. R0's counters
// (VGPR=92, VALUBusy 5%) showed the compiler sinks these loads when left in
// a serial loop -> 4 exposed memory round-trips. grid (B, N/2) x 256.
// ---------------------------------------------------------------------------
template <bool FUSE>
__global__ void __launch_bounds__(256, 2) k_layer(
    const float* __restrict__ q, const float* __restrict__ k,
    const float* __restrict__ v,
    const float* __restrict__ Wo, const float* __restrict__ bo,
    const float* __restrict__ ln1g, const float* __restrict__ ln1b,
    const float* __restrict__ Wff1, const float* __restrict__ bff1,
    const float* __restrict__ Wff2, const float* __restrict__ bff2,
    const float* __restrict__ ln2g, const float* __restrict__ ln2b,
    const float* __restrict__ Wqn, const float* __restrict__ bqn,
    const float* __restrict__ Wkn, const float* __restrict__ bkn,
    const float* __restrict__ Wvn, const float* __restrict__ bvn,
    float* __restrict__ qo, float* __restrict__ ko, float* __restrict__ vo,
    float* __restrict__ x) {
    __shared__ float attS[2][D];
    __shared__ float xs[2][D];
    __shared__ float f1s[2][2 * D];
    __shared__ float ppA[4][2][192];
    __shared__ float ppB[4][2][192];
    int t = threadIdx.x, lane = t & 63, w = t >> 6, ch = lane;
    int b = blockIdx.x, n0 = blockIdx.y * 2;

    size_t xi0 = ((size_t)(b * N + n0)) * D + ch;
    float xv0 = x[xi0], xv1 = x[xi0 + D];
    float bo_r = bo[ch], l1g = ln1g[ch], l1b = ln1b[ch];
    float bf1a = bff1[ch], bf1b = bff1[D + ch];
    float bf2_r = bff2[ch], l2g = ln2g[ch], l2b = ln2b[ch];

    // ---- attention: wave = head; 2-deep pipelined K/V stream ----
    int bh = b * NH + w;
    const float* kb = k + (size_t)bh * N * DH;
    const float* vb = v + (size_t)bh * N * DH;
    const float4* qp0 = (const float4*)(q + ((size_t)bh * N + n0) * DH);
    const float4* qp1 = (const float4*)(q + ((size_t)bh * N + n0 + 1) * DH);

    float4 KA[4], VA[4], KB[4], VB[4];
    ATT_LOAD(KA, VA, 0);                 // chunk 0 in flight
    ATT_LOAD(KB, VB, 1);                 // chunk 1 in flight
    float4 qv0[4], qv1[4];
#pragma unroll
    for (int c = 0; c < 4; ++c) { qv0[c] = qp0[c]; qv1[c] = qp1[c]; }

    float o0[DH], o1[DH];
#pragma unroll
    for (int d = 0; d < DH; ++d) { o0[d] = 0.f; o1[d] = 0.f; }
    float l0 = 0.f, l1 = 0.f;

    ATT_CHUNK(KA, VA);                   // compute 0 (chunk 1 still loading)
    ATT_LOAD(KA, VA, 2);                 // chunk 2 in flight
    ATT_CHUNK(KB, VB);                   // compute 1
    ATT_LOAD(KB, VB, 3);                 // chunk 3 in flight
    ATT_CHUNK(KA, VA);                   // compute 2
    // prefetch Wo while chunk 3 finishes + reductions run
    float wo[16];
#pragma unroll
    for (int i = 0; i < 16; ++i) wo[i] = Wo[(w * 16 + i) * D + ch];
    ATT_CHUNK(KB, VB);                   // compute 3

#pragma unroll
    for (int off = 32; off > 0; off >>= 1) {
        l0 += __shfl_xor(l0, off);
        l1 += __shfl_xor(l1, off);
    }
#pragma unroll
    for (int d = 0; d < DH; ++d) {
#pragma unroll
        for (int off = 32; off > 0; off >>= 1) {
            o0[d] += __shfl_xor(o0[d], off);
            o1[d] += __shfl_xor(o1[d], off);
        }
    }
    float rl0 = 1.f / l0, rl1 = 1.f / l1;
    if (lane < DH) {
        float sel0 = o0[0], sel1 = o1[0];
#pragma unroll
        for (int d = 1; d < DH; ++d)
            if (lane == d) { sel0 = o0[d]; sel1 = o1[d]; }
        attS[0][w * DH + lane] = sel0 * rl0;
        attS[1][w * DH + lane] = sel1 * rl1;
    }
    __syncthreads();

    // ---- O-proj (split-K-4, both tokens) + prefetch Wff1 ----
    {
        float a0 = 0.f, a1 = 0.f;
#pragma unroll
        for (int i = 0; i < 16; ++i) {
            int kk = w * 16 + i;
            float wv = wo[i];
            a0 += attS[0][kk] * wv;
            a1 += attS[1][kk] * wv;
        }
        ppA[w][0][ch] = a0; ppA[w][1][ch] = a1;
    }
    float wf1a[16], wf1b[16];
#pragma unroll
    for (int i = 0; i < 16; ++i) {
        int kk = w * 16 + i;
        wf1a[i] = Wff1[kk * 2 * D + ch];
        wf1b[i] = Wff1[kk * 2 * D + D + ch];
    }
    __syncthreads();

    // ---- LN1 (both tokens, redundant per wave) ----
    float r0 = xv0 + bo_r + ppA[0][0][ch] + ppA[1][0][ch] + ppA[2][0][ch] + ppA[3][0][ch];
    float r1 = xv1 + bo_r + ppA[0][1][ch] + ppA[1][1][ch] + ppA[2][1][ch] + ppA[3][1][ch];
    float s0a = r0, q0a = r0 * r0, s1a = r1, q1a = r1 * r1;
#pragma unroll
    for (int off = 32; off > 0; off >>= 1) {
        s0a += __shfl_xor(s0a, off); q0a += __shfl_xor(q0a, off);
        s1a += __shfl_xor(s1a, off); q1a += __shfl_xor(q1a, off);
    }
    float mean10 = s0a * (1.0f / D), var10 = q0a * (1.0f / D) - mean10 * mean10;
    float mean11 = s1a * (1.0f / D), var11 = q1a * (1.0f / D) - mean11 * mean11;
    float x1_0 = l1g * (r0 - mean10) * rsqrtf(var10 + EPS) + l1b;
    float x1_1 = l1g * (r1 - mean11) * rsqrtf(var11 + EPS) + l1b;
    if (w == 0) xs[0][ch] = x1_0;
    if (w == 1) xs[1][ch] = x1_1;
    __syncthreads();

    // ---- FFN1 (split-K-4, both halves, both tokens) + prefetch Wff2 ----
    {
        float u0=0.f, g0=0.f, u1=0.f, g1=0.f;
#pragma unroll
        for (int i = 0; i < 16; ++i) {
            int kk = w * 16 + i;
            float xx0 = xs[0][kk], xx1 = xs[1][kk];
            u0 += xx0 * wf1a[i]; g0 += xx0 * wf1b[i];
            u1 += xx1 * wf1a[i]; g1 += xx1 * wf1b[i];
        }
        ppB[w][0][ch] = u0; ppB[w][0][64 + ch] = g0;
        ppB[w][1][ch] = u1; ppB[w][1][64 + ch] = g1;
    }
    float wf2[32];
#pragma unroll
    for (int i = 0; i < 32; ++i) wf2[i] = Wff2[(w * 32 + i) * D + ch];
    __syncthreads();

    // ---- ReLU combine -> f1s ----
    {
        float a00 = fmaxf(bf1a + ppB[0][0][ch] + ppB[1][0][ch] + ppB[2][0][ch] + ppB[3][0][ch], 0.f);
        float a01 = fmaxf(bf1b + ppB[0][0][64+ch] + ppB[1][0][64+ch] + ppB[2][0][64+ch] + ppB[3][0][64+ch], 0.f);
        float a10 = fmaxf(bf1a + ppB[0][1][ch] + ppB[1][1][ch] + ppB[2][1][ch] + ppB[3][1][ch], 0.f);
        float a11 = fmaxf(bf1b + ppB[0][1][64+ch] + ppB[1][1][64+ch] + ppB[2][1][64+ch] + ppB[3][1][64+ch], 0.f);
        if (w == 0) { f1s[0][ch] = a00; f1s[0][64 + ch] = a01; }
        if (w == 1) { f1s[1][ch] = a10; f1s[1][64 + ch] = a11; }
    }
    __syncthreads();

    // ---- FFN2 (split-K-4 over 128, both tokens) + prefetch next QKV ----
    {
        float e0 = 0.f, e1 = 0.f;
#pragma unroll
        for (int i = 0; i < 32; ++i) {
            int kk = w * 32 + i;
            float xx0 = f1s[0][kk], xx1 = f1s[1][kk];
            e0 += xx0 * wf2[i];
            e1 += xx1 * wf2[i];
        }
        ppA[w][0][ch] = e0; ppA[w][1][ch] = e1;
    }
    float wqn[16], wkn[16], wvn[16];
    if (FUSE) {
#pragma unroll
        for (int i = 0; i < 16; ++i) {
            int kk = w * 16 + i;
            wqn[i] = Wqn[kk * D + ch];
            wkn[i] = Wkn[kk * D + ch];
            wvn[i] = Wvn[kk * D + ch];
        }
    }
    __syncthreads();

    // ---- LN2 (both tokens, redundant per wave) ----
    float o2_0 = bf2_r + ppA[0][0][ch] + ppA[1][0][ch] + ppA[2][0][ch] + ppA[3][0][ch];
    float o2_1 = bf2_r + ppA[0][1][ch] + ppA[1][1][ch] + ppA[2][1][ch] + ppA[3][1][ch];
    float r20 = x1_0 + o2_0, r21 = x1_1 + o2_1;
    float s0b = r20, q0b = r20 * r20, s1b = r21, q1b = r21 * r21;
#pragma unroll
    for (int off = 32; off > 0; off >>= 1) {
        s0b += __shfl_xor(s0b, off); q0b += __shfl_xor(q0b, off);
        s1b += __shfl_xor(s1b, off); q1b += __shfl_xor(q1b, off);
    }
    float mean20 = s0b * (1.0f / D), var20 = q0b * (1.0f / D) - mean20 * mean20;
    float mean21 = s1b * (1.0f / D), var21 = q1b * (1.0f / D) - mean21 * mean21;
    float xn0 = l2g * (r20 - mean20) * rsqrtf(var20 + EPS) + l2b;
    float xn1 = l2g * (r21 - mean21) * rsqrtf(var21 + EPS) + l2b;
    if (w == 0) x[xi0] = xn0;
    if (w == 1) x[xi0 + D] = xn1;

    // ---- fused next-layer QKV ----
    if (FUSE) {
        if (w == 0) xs[0][ch] = xn0;
        if (w == 1) xs[1][ch] = xn1;
        __syncthreads();
        float aq0=0.f, ak0=0.f, av0=0.f, aq1=0.f, ak1=0.f, av1=0.f;
#pragma unroll
        for (int i = 0; i < 16; ++i) {
            int kk = w * 16 + i;
            float xx0 = xs[0][kk], xx1 = xs[1][kk];
            aq0 += xx0 * wqn[i]; ak0 += xx0 * wkn[i]; av0 += xx0 * wvn[i];
            aq1 += xx1 * wqn[i]; ak1 += xx1 * wkn[i]; av1 += xx1 * wvn[i];
        }
        ppB[w][0][ch] = aq0; ppB[w][0][64 + ch] = ak0; ppB[w][0][128 + ch] = av0;
        ppB[w][1][ch] = aq1; ppB[w][1][64 + ch] = ak1; ppB[w][1][128 + ch] = av1;
        __syncthreads();
        if (w < 3) {
            int o = w * 64;
            int head = ch >> 4, dh = ch & (DH - 1);
#pragma unroll
            for (int tk = 0; tk < 2; ++tk) {
                float val = ppB[0][tk][o+ch] + ppB[1][tk][o+ch] + ppB[2][tk][o+ch] + ppB[3][tk][o+ch];
                size_t oidx = (((size_t)(b * NH + head)) * N + (n0 + tk)) * DH + dh;
                if (w == 0) qo[oidx] = val + bqn[ch];
                else if (w == 1) ko[oidx] = val + bkn[ch];
                else vo[oidx] = val + bvn[ch];
            }
        }
    }
}

extern "C" void kernel_launch(void* const* d_in, const int* in_sizes, int n_in,
                              void* d_out, int out_size, void* d_ws, size_t ws_size,
                              hipStream_t stream) {
    const float* feature = (const float*)d_in[0];
    const float* W1   = (const float*)d_in[1];
    const float* b1   = (const float*)d_in[2];
    const float* mw   = (const float*)d_in[3];
    const float* mb   = (const float*)d_in[4];
    const float* bn_g = (const float*)d_in[5];
    const float* bn_b = (const float*)d_in[6];
    const float* Wq   = (const float*)d_in[7];
    const float* bq   = (const float*)d_in[8];
    const float* Wk   = (const float*)d_in[9];
    const float* bk   = (const float*)d_in[10];
    const float* Wv   = (const float*)d_in[11];
    const float* bv   = (const float*)d_in[12];
    const float* Wo   = (const float*)d_in[13];
    const float* bo   = (const float*)d_in[14];
    const float* ln1g = (const float*)d_in[15];
    const float* ln1b = (const float*)d_in[16];
    const float* Wff1 = (const float*)d_in[17];
    const float* bff1 = (const float*)d_in[18];
    const float* Wff2 = (const float*)d_in[19];
    const float* bff2 = (const float*)d_in[20];
    const float* ln2g = (const float*)d_in[21];
    const float* ln2b = (const float*)d_in[22];

    float* ws    = (float*)d_ws;
    float* rs    = ws;                     // B*N*NH = 4096
    float* bnacc = rs + B * N * NH;        // 128
    float* h     = bnacc + 128;            // B*N*D
    float* q     = h + B * N * D;          // B*N*D
    float* k0    = q + B * N * D;
    float* v0    = k0 + B * N * D;
    float* k1    = v0 + B * N * D;
    float* v1    = k1 + B * N * D;
    float* x     = (float*)d_out;          // running (B,N,D) activation

    k_rowsum<<<256, 512, 0, stream>>>(feature, W1, b1, mw, mb, rs, bnacc);
    k_aggregate<<<256, 512, 0, stream>>>(feature, W1, b1, mw, mb, rs, h, bnacc);
    k_qkv0<<<dim3(B, N / 2), 256, 0, stream>>>(h, bnacc, bn_g, bn_b,
                                               Wq, bq, Wk, bk, Wv, bv, x, q, k0, v0);
    // layer 0 (fused layer-1 QKV into q / k1 / v1), then layer 1
    k_layer<true><<<dim3(B, N / 2), 256, 0, stream>>>(q, k0, v0,
        Wo, bo, ln1g, ln1b, Wff1, bff1, Wff2, bff2, ln2g, ln2b,
        Wq + (size_t)D * D, bq + D, Wk + (size_t)D * D, bk + D,
        Wv + (size_t)D * D, bv + D, q, k1, v1, x);
    k_layer<false><<<dim3(B, N / 2), 256, 0, stream>>>(q, k1, v1,
        Wo + (size_t)D * D, bo + D, ln1g + D, ln1b + D,
        Wff1 + (size_t)D * 2 * D, bff1 + 2 * D,
        Wff2 + (size_t)2 * D * D, bff2 + D, ln2g + D, ln2b + D,
        nullptr, nullptr, nullptr, nullptr, nullptr, nullptr,
        nullptr, nullptr, nullptr, x);
}